// Round 8
// baseline (3097.690 us; speedup 1.0000x reference)
//
#include <hip/hip_runtime.h>

// ---------------------------------------------------------------------------
// BiLSTM-CRF forward loss on MI355X (gfx950).
// R15: R14 + restructured LSTM recurrence (lstm_rec2):
//   16 blocks x 1024 thr: block = (dir, 64-unit slab u8), 16 waves.
//   - handoff participants per consumer: 8 blocks (was 32)
//   - chip-wide h-exchange: 512 KB/step (was 2 MB)
//   - 32 MFMA/wave/step (was 16) -> more latency hiding
//   - gate buffer layout UNCHANGED (address remap derived from the same
//     wave-ordered layout); out layout UNCHANGED; same u64 NaN-sentinel
//     protocol. gemm_nt / prep / CRF are R14-identical.
// Chain: prep -> bert GEMM -> gates0 GEMM -> coop lstm L0 -> gates1 GEMM
//        -> coop lstm L1 -> heads GEMM -> CRF.
// ---------------------------------------------------------------------------

typedef unsigned short u16;
typedef unsigned int u32;
typedef unsigned long long u64;
typedef __attribute__((ext_vector_type(8))) __bf16 bf16x8;
typedef __attribute__((ext_vector_type(4))) float floatx4;

typedef const __attribute__((address_space(1))) u32 gu32;
typedef __attribute__((address_space(3))) u32 lu32;

static __device__ __forceinline__ u16 f2bf(float f) {
  u32 u = __float_as_uint(f);
  u += 0x7fffu + ((u >> 16) & 1u);   // round-to-nearest-even
  return (u16)(u >> 16);
}
static __device__ __forceinline__ u64 pack4(float4 v) {
  return (u64)f2bf(v.x) | ((u64)f2bf(v.y) << 16) |
         ((u64)f2bf(v.z) << 32) | ((u64)f2bf(v.w) << 48);
}
static __device__ __forceinline__ float bf2f(u32 bits) {
  return __uint_as_float(bits << 16);
}
static __device__ __forceinline__ float sigf(float x) {
  return 1.0f / (1.0f + __expf(-x));
}
static __device__ __forceinline__ float tanh_(float x) {
  return 1.0f - 2.0f / (1.0f + __expf(2.0f * x));
}
static __device__ __forceinline__ floatx4 mfma16(bf16x8 a, bf16x8 b, floatx4 c) {
  return __builtin_amdgcn_mfma_f32_16x16x32_bf16(a, b, c, 0, 0, 0);
}
static __device__ __forceinline__ u64 aload64(const u64* p) {
  return __hip_atomic_load((u64*)p, __ATOMIC_RELAXED, __HIP_MEMORY_SCOPE_AGENT);
}
static __device__ __forceinline__ void astore64(u64* p, u64 v) {
  __hip_atomic_store(p, v, __ATOMIC_RELAXED, __HIP_MEMORY_SCOPE_AGENT);
}
// async 16B global->LDS: lds dest = base + lane*16 (base wave-uniform)
static __device__ __forceinline__ void gload16(const u16* g, u16* lds_base) {
  __builtin_amdgcn_global_load_lds((gu32*)g, (lu32*)lds_base, 16, 0, 0);
}

// ---------------------------------------------------------------------------
// prep: vectorized fp32->bf16 conversions + bias sums + d_out=0 + sentinels.
// ---------------------------------------------------------------------------
__global__ __launch_bounds__(256) void prep_kernel(
    const float* __restrict__ w_ih, const float* __restrict__ w_hh,
    const float* __restrict__ b_ih, const float* __restrict__ b_hh,
    const float* __restrict__ src,  const float* __restrict__ bert,
    const float* __restrict__ hwp,  const float* __restrict__ hbp,
    const float* __restrict__ hwm,  const float* __restrict__ hbm,
    u16* __restrict__ Wsrc, u16* __restrict__ Wbert, u16* __restrict__ Wih1,
    u16* __restrict__ Whh,  u16* __restrict__ SrcBf, u16* __restrict__ BertBf,
    u16* __restrict__ Wheads, float* __restrict__ b0sum, float* __restrict__ b1sum,
    float* __restrict__ hb, float* __restrict__ dout,
    u64* __restrict__ out0s, u64* __restrict__ out1s)
{
  const int A4 = 1048576;  // w_ih layer0 float4s -> Wsrc / Wbert
  const int B4 = 1048576;  // w_ih layer1 -> Wih1
  const int C4 = 1048576;  // w_hh -> Whh
  const int D4 = 262144;   // src -> SrcBf
  const int E4 = 6144;     // bert -> BertBf
  const int F4 = 24576;    // head weights -> Wheads
  const int G4 = 2048;     // bias sums (fp32)
  const int H4 = 24;       // head bias (fp32)
  const int NI = 2097152;  // sentinel u64 fills (out0 + out1)
  const int TOTAL = A4 + B4 + C4 + D4 + E4 + F4 + G4 + H4 + 1 + NI;
  for (int i = blockIdx.x * 256 + threadIdx.x; i < TOTAL; i += gridDim.x * 256) {
    int x = i;
    if (x < A4) {
      const int e = x * 4, c = e & 1023, r = e >> 10;   // r = dir*2048 + row
      const u64 pk = pack4(*(const float4*)&w_ih[e]);
      if (c < 256) *(u64*)&Wsrc[r * 256 + c] = pk;
      else         *(u64*)&Wbert[r * 768 + (c - 256)] = pk;
      continue;
    }
    x -= A4;
    if (x < B4) {
      *(u64*)&Wih1[x * 4] = pack4(*(const float4*)&w_ih[4194304 + x * 4]);
      continue;
    }
    x -= B4;
    if (x < C4) {
      *(u64*)&Whh[x * 4] = pack4(*(const float4*)&w_hh[x * 4]);
      continue;
    }
    x -= C4;
    if (x < D4) {
      *(u64*)&SrcBf[x * 4] = pack4(*(const float4*)&src[x * 4]);
      continue;
    }
    x -= D4;
    if (x < E4) {
      *(u64*)&BertBf[x * 4] = pack4(*(const float4*)&bert[x * 4]);
      continue;
    }
    x -= E4;
    if (x < F4) {
      const int e = x * 4;
      const float4 v = (e < 32768) ? *(const float4*)&hwp[e]
                                   : *(const float4*)&hwm[e - 32768];
      *(u64*)&Wheads[e] = pack4(v);
      continue;
    }
    x -= F4;
    if (x < G4) {
      const int e = x * 4;
      const float4 a = *(const float4*)&b_ih[e];
      const float4 b = *(const float4*)&b_hh[e];
      const float4 v = {a.x + b.x, a.y + b.y, a.z + b.z, a.w + b.w};
      if (e < 4096) *(float4*)&b0sum[e] = v;
      else          *(float4*)&b1sum[e - 4096] = v;
      continue;
    }
    x -= G4;
    if (x < H4) {
      const int e = x * 4;
      const float4 v = (e < 32) ? *(const float4*)&hbp[e]
                                : *(const float4*)&hbm[e - 32];
      *(float4*)&hb[e] = v;
      continue;
    }
    x -= H4;
    if (x == 0) { dout[0] = 0.f; continue; }
    x -= 1;
    // sentinel fill: bf16 0xFFFF = NaN, unreachable for valid h in (-1,1)
    if (x < 1048576) out0s[x] = ~0ULL;
    else             out1s[x - 1048576] = ~0ULL;
  }
}

// ---------------------------------------------------------------------------
// bf16 NT GEMM: acc[m][n] = sum_k A[m][k]*B[n][k] (+bias[n]) (+aux[m%32][n])
// 128x128 tile, BK=64, XOR-swizzled LDS, global_load_lds staging.
// mode 0: C fp32. mode 1: bf16 gates, wave-ordered u64 layout (R7-exact).
// ---------------------------------------------------------------------------
__global__ __launch_bounds__(256) void gemm_nt(
    const u16* __restrict__ A, int lda,
    const u16* __restrict__ B, int ldb,
    float* __restrict__ C, int ldc,
    int M, int N, int K,
    const float* __restrict__ bias_n,
    const float* __restrict__ auxBN, int auxld,
    int mode)
{
  __shared__ __align__(16) u16 As[128 * 64];
  __shared__ __align__(16) u16 Bs[128 * 64];
  const int m0 = blockIdx.y * 128, n0 = blockIdx.x * 128;
  const int tid = threadIdx.x;
  const int wv = tid >> 6, ln = tid & 63;
  const int wm = wv & 1, wn = wv >> 1;
  const int q = ln >> 4, l15 = ln & 15;
  floatx4 acc[4][4];
#pragma unroll
  for (int a = 0; a < 4; ++a)
#pragma unroll
    for (int b2 = 0; b2 < 4; ++b2) acc[a][b2] = (floatx4){0.f, 0.f, 0.f, 0.f};

  for (int kk = 0; kk < K; kk += 64) {
    __syncthreads();
#pragma unroll
    for (int j = 0; j < 4; ++j) {
      const int idx = j * 256 + tid;          // linear LDS chunk id (16B units)
      const int r = idx >> 3;                 // tile row
      const int cc = (idx & 7) ^ (r & 7);     // swizzle-corrected source chunk
      const int cb = __builtin_amdgcn_readfirstlane((j * 256 + wv * 64) * 8);
      const int ra = min(m0 + r, M - 1);
      gload16(&A[(long)ra * lda + kk + cc * 8], &As[cb]);
      const int rb = min(n0 + r, N - 1);
      gload16(&B[(long)rb * ldb + kk + cc * 8], &Bs[cb]);
    }
    __syncthreads();
#pragma unroll
    for (int ks = 0; ks < 2; ++ks) {
      bf16x8 af[4], bf[4];
#pragma unroll
      for (int im = 0; im < 4; ++im) {
        const int r = wm * 64 + im * 16 + l15;
        const int slot = (ks * 4 + q) ^ (r & 7);
        af[im] = *(const bf16x8*)&As[r * 64 + slot * 8];
      }
#pragma unroll
      for (int jn = 0; jn < 4; ++jn) {
        const int r = wn * 64 + jn * 16 + l15;
        const int slot = (ks * 4 + q) ^ (r & 7);
        bf[jn] = *(const bf16x8*)&Bs[r * 64 + slot * 8];
      }
#pragma unroll
      for (int im = 0; im < 4; ++im)
#pragma unroll
        for (int jn = 0; jn < 4; ++jn)
          acc[im][jn] = mfma16(af[im], bf[jn], acc[im][jn]);
    }
  }
  // epilogue: C/D layout col=lane&15, row=(lane>>4)*4+reg
  if (mode == 0) {
#pragma unroll
    for (int im = 0; im < 4; ++im)
#pragma unroll
      for (int jn = 0; jn < 4; ++jn) {
        const int n = n0 + wn * 64 + jn * 16 + l15;
        if (n < N) {
          const float badd = bias_n ? bias_n[n] : 0.f;
#pragma unroll
          for (int rg = 0; rg < 4; ++rg) {
            const int m = m0 + wm * 64 + im * 16 + q * 4 + rg;
            if (m < M) {
              float v = acc[im][jn][rg] + badd;
              if (auxBN) v += auxBN[(long)(m & 31) * auxld + n];
              C[(long)m * ldc + n] = v;
            }
          }
        }
      }
  } else {
    u64* G = (u64*)C;
#pragma unroll
    for (int im = 0; im < 4; ++im)
#pragma unroll
      for (int jn = 0; jn < 4; ++jn) {
        const int n = n0 + wn * 64 + jn * 16 + l15;
        const int dirsel = n >> 11, nn = n & 2047;
        const int gt = nn >> 9, u = nn & 511;
        const int ub = u >> 4, low = u & 15;
        const int wvl = low >> 2, jl = low & 3;
        const int l15l = gt * 4 + jl;
        const int m = m0 + wm * 64 + im * 16 + q * 4;   // rg=0 row
        const int s = m >> 5, b0 = m & 31;
        const int mh = b0 >> 4, qq = (b0 >> 2) & 3;
        const float badd = bias_n ? bias_n[n] : 0.f;
        u64 pk = 0;
#pragma unroll
        for (int rg = 0; rg < 4; ++rg) {
          float v = acc[im][jn][rg] + badd;
          if (auxBN) v += auxBN[(long)(b0 + rg) * auxld + n];
          pk |= (u64)f2bf(v) << (16 * rg);
        }
        G[(((((long)dirsel * 128 + s) * 2 + mh) * 32 + ub) * 4 + wvl) * 64
          + l15l * 4 + qq] = pk;
      }
  }
}

// ---------------------------------------------------------------------------
// LSTM recurrence v2: 16 blocks x 1024 thr. block = (dir, 64-unit slab u8).
// Wave w handles units u8*64 + w*4 .. +3 for ALL 32 batches (both mh halves).
// Gate entry (same wave-ordered buffer as before):
//   dir*2097152 + s*16384 + mh*8192 + (u8*4+(w>>2))*256 + (w&3)*64 + l15*4+q
// h exchange: per step each block loads h(t-1) [32 batches][512 units] of its
// dir (4096 u64) with the u64 NaN-sentinel retry; producers = 8 blocks/dir.
// Self-sync: a wave's t+1 sentinel pass requires all own-block waves' step-t
// stores -> no WAR on h_lds.
// ---------------------------------------------------------------------------
__global__ __launch_bounds__(1024, 1) void lstm_rec2(
    const u16* __restrict__ gates,  // wave-ordered, see gemm_nt mode 1
    u16* __restrict__ out,          // [128][32][1024] bf16 (fwd | bwd)
    const u16* __restrict__ whh)    // [2][2048][512] bf16 (this layer)
{
  __shared__ __align__(16) u16 h_lds[32 * 512];   // 32 KiB
  __shared__ float gsc[16][16][17];               // 17 KiB
  const int bid = blockIdx.x;       // 16 blocks
  const int dir = bid >> 3;
  const int u8b = bid & 7;          // 64-unit slab
  const int tid = threadIdx.x;
  const int w = tid >> 6;           // wave 0..15
  const int ln = tid & 63;
  const int q = ln >> 4, l15 = ln & 15;

  // B-frag column n=l15 -> gate row: gate=(l15>>2), unit offset=(l15&3)
  const int gate_r = (l15 >> 2) * 512 + u8b * 64 + w * 4 + (l15 & 3);

  bf16x8 bfrag[16];
  {
    const u16* wp = whh + ((long)dir * 2048 + gate_r) * 512 + q * 8;
#pragma unroll
    for (int ks = 0; ks < 16; ++ks)
      bfrag[ks] = *(const bf16x8*)(wp + ks * 32);
  }

  float c0 = 0.f, c1 = 0.f;   // cell states (mh=0 / mh=1) for (batch=l15, unit=w*4+q)

  // gate pointer (u64 units); per-s stride 16384, mh stride 8192
  const u64* gb = (const u64*)gates + (long)dir * 2097152
      + (long)(u8b * 4 + (w >> 2)) * 256 + (w & 3) * 64 + l15 * 4 + q;

  const long s0 = (long)(dir ? 127 : 0) * 16384;
  u64 gcur0 = gb[s0];
  u64 gcur1 = gb[s0 + 8192];
  u64 gnext0 = 0, gnext1 = 0;

  for (int t = 0; t < 128; ++t) {
    const int s = dir ? (127 - t) : t;
    if (t < 127) {
      const long sn = (long)(dir ? (126 - t) : (t + 1)) * 16384;
      gnext0 = gb[sn];
      gnext1 = gb[sn + 8192];
    }
    floatx4 a0 = (floatx4){0.f, 0.f, 0.f, 0.f};
    floatx4 b0 = (floatx4){0.f, 0.f, 0.f, 0.f};
    if (t > 0) {
      const int sp = dir ? (s + 1) : (s - 1);
      // h(t-1): 32 rows x 128 u64 for this dir
      const u64* ubp = (const u64*)out + (long)sp * 8192 + dir * 128;
      u64 v4[4];
#pragma unroll
      for (int j = 0; j < 4; ++j) {
        const int idx = j * 1024 + tid;          // 4096 u64 chunks
        const int r = idx >> 7, c4 = idx & 127;  // row(batch), u64-in-row
        v4[j] = aload64(ubp + (long)r * 256 + c4);
      }
      while (true) {
        bool bad = false;
#pragma unroll
        for (int j = 0; j < 4; ++j) bad |= ((v4[j] & 0xffffULL) == 0xffffULL);
        if (!bad) break;
#pragma unroll
        for (int j = 0; j < 4; ++j) {
          if ((v4[j] & 0xffffULL) == 0xffffULL) {
            const int idx = j * 1024 + tid;
            const int r = idx >> 7, c4 = idx & 127;
            v4[j] = aload64(ubp + (long)r * 256 + c4);
          }
        }
      }
#pragma unroll
      for (int j = 0; j < 4; ++j) {
        const int idx = j * 1024 + tid;
        const int r = idx >> 7, c4 = idx & 127;
        const int cc8 = c4 >> 1, hf = c4 & 1;
        *(u64*)&h_lds[r * 512 + ((cc8 ^ (r & 7)) << 3) + (hf << 2)] = v4[j];
      }
      __syncthreads();   // the ONLY barrier per step
      // 4 independent MFMA chains: {mh0,mh1} x {even,odd ks}
      floatx4 a1 = (floatx4){0.f, 0.f, 0.f, 0.f};
      floatx4 b1 = (floatx4){0.f, 0.f, 0.f, 0.f};
      const u16* row0 = &h_lds[l15 * 512];          // mh=0 rows (r&7 == l15&7)
      const u16* row1 = &h_lds[(16 + l15) * 512];   // mh=1 rows (same &7)
#pragma unroll
      for (int ks = 0; ks < 16; ks += 2) {
        const int sl0 = ((ks * 4 + q) ^ (l15 & 7)) << 3;
        const int sl1 = (((ks + 1) * 4 + q) ^ (l15 & 7)) << 3;
        a0 = mfma16(*(const bf16x8*)&row0[sl0], bfrag[ks], a0);
        b0 = mfma16(*(const bf16x8*)&row1[sl0], bfrag[ks], b0);
        a1 = mfma16(*(const bf16x8*)&row0[sl1], bfrag[ks + 1], a1);
        b1 = mfma16(*(const bf16x8*)&row1[sl1], bfrag[ks + 1], b1);
      }
      a0 += a1;
      b0 += b1;
    }
    // ---- mh = 0: C-frag (row=batch=q*4+rg, col=n=l15) -> wave-local LDS ----
#pragma unroll
    for (int rg = 0; rg < 4; ++rg)
      gsc[w][q * 4 + rg][l15] = a0[rg] + bf2f((u32)((gcur0 >> (16 * rg)) & 0xffffu));
    {
      const float gi = gsc[w][l15][q];
      const float gf = gsc[w][l15][4 + q];
      const float gg = gsc[w][l15][8 + q];
      const float go = gsc[w][l15][12 + q];
      const float iv = sigf(gi), fv = sigf(gf), gv = tanh_(gg), ov = sigf(go);
      c0 = fv * c0 + iv * gv;
      const float h = ov * tanh_(c0);
      const u32 hv = (u32)f2bf(h);
      const u32 p1 = (u32)__shfl_xor((int)hv, 16);
      const u32 lo32 = hv | (p1 << 16);
      const u64 w64 = (u64)lo32 | ((u64)(u32)__shfl_xor((int)lo32, 32) << 32);
      if (q == 0)
        astore64((u64*)&out[((long)s * 32 + l15) * 1024 + dir * 512 + u8b * 64 + w * 4],
                 w64);
    }
    // ---- mh = 1 (reuses gsc[w]: wave-synchronous) ----
#pragma unroll
    for (int rg = 0; rg < 4; ++rg)
      gsc[w][q * 4 + rg][l15] = b0[rg] + bf2f((u32)((gcur1 >> (16 * rg)) & 0xffffu));
    {
      const float gi = gsc[w][l15][q];
      const float gf = gsc[w][l15][4 + q];
      const float gg = gsc[w][l15][8 + q];
      const float go = gsc[w][l15][12 + q];
      const float iv = sigf(gi), fv = sigf(gf), gv = tanh_(gg), ov = sigf(go);
      c1 = fv * c1 + iv * gv;
      const float h = ov * tanh_(c1);
      const u32 hv = (u32)f2bf(h);
      const u32 p1 = (u32)__shfl_xor((int)hv, 16);
      const u32 lo32 = hv | (p1 << 16);
      const u64 w64 = (u64)lo32 | ((u64)(u32)__shfl_xor((int)lo32, 32) << 32);
      if (q == 0)
        astore64((u64*)&out[((long)s * 32 + 16 + l15) * 1024 + dir * 512 + u8b * 64 + w * 4],
                 w64);
    }
    gcur0 = gnext0;
    gcur1 = gnext1;
  }
}

// ---------------------------------------------------------------------------
// CRF: one block per (task, batch). Double-buffered alpha: 1 barrier/step.
// ---------------------------------------------------------------------------
template <int K>
static __device__ void crf_body(const float* __restrict__ feat, int off,
                                const int* __restrict__ labels, int b,
                                const float* __restrict__ start,
                                const float* __restrict__ end_,
                                const float* __restrict__ trans,
                                float* __restrict__ outp,
                                float* transT, float (*alpha)[64],
                                float* red)
{
  const int tid = threadIdx.x;
  for (int i = tid; i < K * K; i += 256) {
    int kk = i / K, kp2 = i % K;
    transT[kp2 * 65 + kk] = trans[i];
  }
  if (tid < K) alpha[0][tid] = start[tid] + feat[b * 96 + off + tid];
  __syncthreads();
  constexpr int Kq = K / 4;
  const int kp = tid >> 2, k4 = tid & 3;
  const bool act = kp < K;
  int p = 0;
  for (int s = 1; s < 128; ++s) {
    float x[Kq];
    float mx = -3e38f;
    if (act) {
      const float* tr = &transT[kp * 65 + k4 * Kq];
      const float* al = &alpha[p][k4 * Kq];
#pragma unroll
      for (int i2 = 0; i2 < Kq; ++i2) { x[i2] = al[i2] + tr[i2]; mx = fmaxf(mx, x[i2]); }
    }
    mx = fmaxf(mx, __shfl_xor(mx, 1));
    mx = fmaxf(mx, __shfl_xor(mx, 2));
    float ss = 0.f;
    if (act) {
#pragma unroll
      for (int i2 = 0; i2 < Kq; ++i2) ss += __expf(x[i2] - mx);
    }
    ss += __shfl_xor(ss, 1);
    ss += __shfl_xor(ss, 2);
    if (act && k4 == 0)
      alpha[p ^ 1][kp] = mx + __logf(ss) + feat[(s * 32 + b) * 96 + off + kp];
    __syncthreads();
    p ^= 1;
  }
  // numerator terms (one per time step)
  if (tid < 128) {
    const int tg = labels[tid * 32 + b];
    float term = feat[(tid * 32 + b) * 96 + off + tg];
    if (tid == 0) term += start[tg];
    else          term += trans[labels[(tid - 1) * 32 + b] * K + tg];
    if (tid == 127) term += end_[tg];
    red[tid] = term;
  }
  __syncthreads();
  if (tid == 0) {
    float num = 0.f;
    for (int i = 0; i < 128; ++i) num += red[i];
    float mx = -3e38f;
    for (int k = 0; k < K; ++k) mx = fmaxf(mx, alpha[p][k] + end_[k]);
    float ss = 0.f;
    for (int k = 0; k < K; ++k) ss += __expf(alpha[p][k] + end_[k] - mx);
    const float den = mx + __logf(ss);
    atomicAdd(outp, den - num);   // loss contribution = -(num - den)
  }
}

__global__ __launch_bounds__(256) void crf_kernel(
    const float* __restrict__ feat,
    const int* __restrict__ labp, const int* __restrict__ labm,
    const float* __restrict__ stp, const float* __restrict__ enp, const float* __restrict__ trp,
    const float* __restrict__ stm, const float* __restrict__ enm, const float* __restrict__ trm,
    float* __restrict__ outp)
{
  __shared__ float transT[64 * 65];
  __shared__ float alpha[2][64];
  __shared__ float red[128];
  const int task = blockIdx.x >> 5, b = blockIdx.x & 31;
  if (task == 0) crf_body<32>(feat, 0,  labp, b, stp, enp, trp, outp, transT, alpha, red);
  else           crf_body<64>(feat, 32, labm, b, stm, enm, trm, outp, transT, alpha, red);
}

// ---------------------------------------------------------------------------
// launch
// ---------------------------------------------------------------------------
extern "C" void kernel_launch(void* const* d_in, const int* in_sizes, int n_in,
                              void* d_out, int out_size, void* d_ws, size_t ws_size,
                              hipStream_t stream) {
  const float* src  = (const float*)d_in[0];
  const float* bert = (const float*)d_in[1];
  const int*   labp = (const int*)d_in[2];
  const int*   labm = (const int*)d_in[3];
  const float* w_ih = (const float*)d_in[4];
  const float* w_hh = (const float*)d_in[5];
  const float* b_ih = (const float*)d_in[6];
  const float* b_hh = (const float*)d_in[7];
  const float* hwp  = (const float*)d_in[8];
  const float* hbp  = (const float*)d_in[9];
  const float* hwm  = (const float*)d_in[10];
  const float* hbm  = (const float*)d_in[11];
  const float* stp  = (const float*)d_in[12];
  const float* enp  = (const float*)d_in[13];
  const float* trp  = (const float*)d_in[14];
  const float* stm  = (const float*)d_in[15];
  const float* enm  = (const float*)d_in[16];
  const float* trm  = (const float*)d_in[17];

  char* ws = (char*)d_ws;
  u16*   Wsrc     = (u16*)(ws + 0);          // 4096x256 bf16
  u16*   Wbert    = (u16*)(ws + 2097152);    // 4096x768 bf16
  u16*   Wih1     = (u16*)(ws + 8388608);    // 4096x1024 bf16
  u16*   Whh      = (u16*)(ws + 16777216);   // [2][2][2048][512] bf16
  u16*   SrcBf    = (u16*)(ws + 25165824);   // 4096x256 bf16
  u16*   BertBf   = (u16*)(ws + 27262976);   // 32x768 bf16
  u16*   Wheads   = (u16*)(ws + 27312128);   // 96x1024 bf16
  float* b0sum    = (float*)(ws + 27508736); // [4096]
  float* b1sum    = (float*)(ws + 27525120); // [4096]
  float* hb       = (float*)(ws + 27541504); // [96]
  float* bertpart = (float*)(ws + 27542272); // [32][4096]
  float* feat     = (float*)(ws + 28066560); // [4096][96]
  u16*   out0     = (u16*)(ws + 29639424);   // [128][32][1024] bf16
  u16*   out1     = (u16*)(ws + 38028032);   // [128][32][1024] bf16
  u16*   gates    = (u16*)(ws + 46416640);   // wave-ordered bf16 (32 MiB)
  float* dout     = (float*)d_out;

  // prep: conversions + bias sums + dout=0 + sentinel fill of out0/out1
  hipLaunchKernelGGL(prep_kernel, dim3(2048), dim3(256), 0, stream,
      w_ih, w_hh, b_ih, b_hh, src, bert, hwp, hbp, hwm, hbm,
      Wsrc, Wbert, Wih1, Whh, SrcBf, BertBf, Wheads, b0sum, b1sum, hb, dout,
      (u64*)out0, (u64*)out1);

  // bert part: [32,768]@[4096,768]^T + (b_ih0+b_hh0) -> bertpart[32][4096]
  hipLaunchKernelGGL(gemm_nt, dim3(32, 1), dim3(256), 0, stream,
      BertBf, 768, Wbert, 768, bertpart, 4096, 32, 4096, 768,
      b0sum, (const float*)nullptr, 0, 0);

  // layer0 input proj: src@Wsrc^T + bertpart -> bf16 gates (wave-ordered)
  hipLaunchKernelGGL(gemm_nt, dim3(32, 32), dim3(256), 0, stream,
      SrcBf, 256, Wsrc, 256, (float*)gates, 0, 4096, 4096, 256,
      (const float*)nullptr, bertpart, 4096, 1);

  {
    const u16* g = gates; u16* o = out0; const u16* wh = Whh;
    void* args[] = {&g, &o, &wh};
    if (hipLaunchCooperativeKernel(reinterpret_cast<void*>(&lstm_rec2),
                                   dim3(16), dim3(1024), args, 0, stream)
        != hipSuccess) {
      hipLaunchKernelGGL(lstm_rec2, dim3(16), dim3(1024), 0, stream, g, o, wh);
    }
  }

  // layer1 input proj: out0@Wih1^T + b1sum -> bf16 gates (wave-ordered)
  hipLaunchKernelGGL(gemm_nt, dim3(32, 32), dim3(256), 0, stream,
      out0, 1024, Wih1, 1024, (float*)gates, 0, 4096, 4096, 1024,
      b1sum, (const float*)nullptr, 0, 1);

  {
    const u16* g = gates; u16* o = out1; const u16* wh = Whh + 2L * 2048 * 512;
    void* args[] = {&g, &o, &wh};
    if (hipLaunchCooperativeKernel(reinterpret_cast<void*>(&lstm_rec2),
                                   dim3(16), dim3(1024), args, 0, stream)
        != hipSuccess) {
      hipLaunchKernelGGL(lstm_rec2, dim3(16), dim3(1024), 0, stream, g, o, wh);
    }
  }

  // heads: out1@[96,1024]^T + hb -> feat[4096][96]
  hipLaunchKernelGGL(gemm_nt, dim3(1, 32), dim3(256), 0, stream,
      out1, 1024, Wheads, 1024, feat, 96, 4096, 96, 1024,
      hb, (const float*)nullptr, 0, 0);

  hipLaunchKernelGGL(crf_kernel, dim3(64), dim3(256), 0, stream,
      feat, labp, labm, stp, enp, trp, stm, enm, trm, dout);
}

// Round 9
// 872.169 us; speedup vs baseline: 3.5517x; 3.5517x over previous
//
#include <hip/hip_runtime.h>

// ---------------------------------------------------------------------------
// BiLSTM-CRF forward loss on MI355X (gfx950).
// R16 = R14 revert (best verified: 872 us). R15's 16x1024 lstm restructure
// regressed 6x: per-CU agent-atomic-load throughput is the binding
// constraint on the h-handoff, so the 128-block spread is near-optimal.
//   - prep vectorized (float4 -> packed u64 bf16), sentinels folded in.
//   - gemm_nt with global_load_lds staging, source-side XOR swizzle.
//   - lstm_rec: R7 protocol, 4 independent MFMA chains.
// Chain: prep -> bert GEMM -> gates0 GEMM -> coop lstm L0 -> gates1 GEMM
//        -> coop lstm L1 -> heads GEMM -> CRF.
// ---------------------------------------------------------------------------

typedef unsigned short u16;
typedef unsigned int u32;
typedef unsigned long long u64;
typedef __attribute__((ext_vector_type(8))) __bf16 bf16x8;
typedef __attribute__((ext_vector_type(4))) float floatx4;

typedef const __attribute__((address_space(1))) u32 gu32;
typedef __attribute__((address_space(3))) u32 lu32;

static __device__ __forceinline__ u16 f2bf(float f) {
  u32 u = __float_as_uint(f);
  u += 0x7fffu + ((u >> 16) & 1u);   // round-to-nearest-even
  return (u16)(u >> 16);
}
static __device__ __forceinline__ u64 pack4(float4 v) {
  return (u64)f2bf(v.x) | ((u64)f2bf(v.y) << 16) |
         ((u64)f2bf(v.z) << 32) | ((u64)f2bf(v.w) << 48);
}
static __device__ __forceinline__ float bf2f(u32 bits) {
  return __uint_as_float(bits << 16);
}
static __device__ __forceinline__ float sigf(float x) {
  return 1.0f / (1.0f + __expf(-x));
}
static __device__ __forceinline__ float tanh_(float x) {
  return 1.0f - 2.0f / (1.0f + __expf(2.0f * x));
}
static __device__ __forceinline__ floatx4 mfma16(bf16x8 a, bf16x8 b, floatx4 c) {
  return __builtin_amdgcn_mfma_f32_16x16x32_bf16(a, b, c, 0, 0, 0);
}
static __device__ __forceinline__ u64 aload64(const u64* p) {
  return __hip_atomic_load((u64*)p, __ATOMIC_RELAXED, __HIP_MEMORY_SCOPE_AGENT);
}
static __device__ __forceinline__ void astore64(u64* p, u64 v) {
  __hip_atomic_store(p, v, __ATOMIC_RELAXED, __HIP_MEMORY_SCOPE_AGENT);
}
// async 16B global->LDS: lds dest = base + lane*16 (base wave-uniform)
static __device__ __forceinline__ void gload16(const u16* g, u16* lds_base) {
  __builtin_amdgcn_global_load_lds((gu32*)g, (lu32*)lds_base, 16, 0, 0);
}

// ---------------------------------------------------------------------------
// prep: vectorized fp32->bf16 conversions + bias sums + d_out=0 + sentinels.
// All section boundaries are %4==0, so a float4 chunk never straddles one.
// ---------------------------------------------------------------------------
__global__ __launch_bounds__(256) void prep_kernel(
    const float* __restrict__ w_ih, const float* __restrict__ w_hh,
    const float* __restrict__ b_ih, const float* __restrict__ b_hh,
    const float* __restrict__ src,  const float* __restrict__ bert,
    const float* __restrict__ hwp,  const float* __restrict__ hbp,
    const float* __restrict__ hwm,  const float* __restrict__ hbm,
    u16* __restrict__ Wsrc, u16* __restrict__ Wbert, u16* __restrict__ Wih1,
    u16* __restrict__ Whh,  u16* __restrict__ SrcBf, u16* __restrict__ BertBf,
    u16* __restrict__ Wheads, float* __restrict__ b0sum, float* __restrict__ b1sum,
    float* __restrict__ hb, float* __restrict__ dout,
    u64* __restrict__ out0s, u64* __restrict__ out1s)
{
  const int A4 = 1048576;  // w_ih layer0 float4s -> Wsrc / Wbert
  const int B4 = 1048576;  // w_ih layer1 -> Wih1
  const int C4 = 1048576;  // w_hh -> Whh
  const int D4 = 262144;   // src -> SrcBf
  const int E4 = 6144;     // bert -> BertBf
  const int F4 = 24576;    // head weights -> Wheads
  const int G4 = 2048;     // bias sums (fp32)
  const int H4 = 24;       // head bias (fp32)
  const int NI = 2097152;  // sentinel u64 fills (out0 + out1)
  const int TOTAL = A4 + B4 + C4 + D4 + E4 + F4 + G4 + H4 + 1 + NI;
  for (int i = blockIdx.x * 256 + threadIdx.x; i < TOTAL; i += gridDim.x * 256) {
    int x = i;
    if (x < A4) {
      const int e = x * 4, c = e & 1023, r = e >> 10;   // r = dir*2048 + row
      const u64 pk = pack4(*(const float4*)&w_ih[e]);
      if (c < 256) *(u64*)&Wsrc[r * 256 + c] = pk;
      else         *(u64*)&Wbert[r * 768 + (c - 256)] = pk;
      continue;
    }
    x -= A4;
    if (x < B4) {
      *(u64*)&Wih1[x * 4] = pack4(*(const float4*)&w_ih[4194304 + x * 4]);
      continue;
    }
    x -= B4;
    if (x < C4) {
      *(u64*)&Whh[x * 4] = pack4(*(const float4*)&w_hh[x * 4]);
      continue;
    }
    x -= C4;
    if (x < D4) {
      *(u64*)&SrcBf[x * 4] = pack4(*(const float4*)&src[x * 4]);
      continue;
    }
    x -= D4;
    if (x < E4) {
      *(u64*)&BertBf[x * 4] = pack4(*(const float4*)&bert[x * 4]);
      continue;
    }
    x -= E4;
    if (x < F4) {
      const int e = x * 4;
      const float4 v = (e < 32768) ? *(const float4*)&hwp[e]
                                   : *(const float4*)&hwm[e - 32768];
      *(u64*)&Wheads[e] = pack4(v);
      continue;
    }
    x -= F4;
    if (x < G4) {
      const int e = x * 4;
      const float4 a = *(const float4*)&b_ih[e];
      const float4 b = *(const float4*)&b_hh[e];
      const float4 v = {a.x + b.x, a.y + b.y, a.z + b.z, a.w + b.w};
      if (e < 4096) *(float4*)&b0sum[e] = v;
      else          *(float4*)&b1sum[e - 4096] = v;
      continue;
    }
    x -= G4;
    if (x < H4) {
      const int e = x * 4;
      const float4 v = (e < 32) ? *(const float4*)&hbp[e]
                                : *(const float4*)&hbm[e - 32];
      *(float4*)&hb[e] = v;
      continue;
    }
    x -= H4;
    if (x == 0) { dout[0] = 0.f; continue; }
    x -= 1;
    // sentinel fill: bf16 0xFFFF = NaN, unreachable for valid h in (-1,1)
    if (x < 1048576) out0s[x] = ~0ULL;
    else             out1s[x - 1048576] = ~0ULL;
  }
}

// ---------------------------------------------------------------------------
// bf16 NT GEMM: acc[m][n] = sum_k A[m][k]*B[n][k] (+bias[n]) (+aux[m%32][n])
// 128x128 tile, BK=64, XOR-swizzled LDS. Staging via global_load_lds: the
// LDS destination is linear (wave base + lane*16); the swizzle is applied by
// permuting the per-lane SOURCE chunk: cc = (idx&7) ^ ((idx>>3)&7).
// mode 0: C fp32. mode 1: bf16 gates, wave-ordered u64 layout (R7-exact).
// ---------------------------------------------------------------------------
__global__ __launch_bounds__(256) void gemm_nt(
    const u16* __restrict__ A, int lda,
    const u16* __restrict__ B, int ldb,
    float* __restrict__ C, int ldc,
    int M, int N, int K,
    const float* __restrict__ bias_n,
    const float* __restrict__ auxBN, int auxld,
    int mode)
{
  __shared__ __align__(16) u16 As[128 * 64];
  __shared__ __align__(16) u16 Bs[128 * 64];
  const int m0 = blockIdx.y * 128, n0 = blockIdx.x * 128;
  const int tid = threadIdx.x;
  const int wv = tid >> 6, ln = tid & 63;
  const int wm = wv & 1, wn = wv >> 1;
  const int q = ln >> 4, l15 = ln & 15;
  floatx4 acc[4][4];
#pragma unroll
  for (int a = 0; a < 4; ++a)
#pragma unroll
    for (int b2 = 0; b2 < 4; ++b2) acc[a][b2] = (floatx4){0.f, 0.f, 0.f, 0.f};

  for (int kk = 0; kk < K; kk += 64) {
    __syncthreads();
#pragma unroll
    for (int j = 0; j < 4; ++j) {
      const int idx = j * 256 + tid;          // linear LDS chunk id (16B units)
      const int r = idx >> 3;                 // tile row
      const int cc = (idx & 7) ^ (r & 7);     // swizzle-corrected source chunk
      const int cb = __builtin_amdgcn_readfirstlane((j * 256 + wv * 64) * 8);
      const int ra = min(m0 + r, M - 1);
      gload16(&A[(long)ra * lda + kk + cc * 8], &As[cb]);
      const int rb = min(n0 + r, N - 1);
      gload16(&B[(long)rb * ldb + kk + cc * 8], &Bs[cb]);
    }
    __syncthreads();
#pragma unroll
    for (int ks = 0; ks < 2; ++ks) {
      bf16x8 af[4], bf[4];
#pragma unroll
      for (int im = 0; im < 4; ++im) {
        const int r = wm * 64 + im * 16 + l15;
        const int slot = (ks * 4 + q) ^ (r & 7);
        af[im] = *(const bf16x8*)&As[r * 64 + slot * 8];
      }
#pragma unroll
      for (int jn = 0; jn < 4; ++jn) {
        const int r = wn * 64 + jn * 16 + l15;
        const int slot = (ks * 4 + q) ^ (r & 7);
        bf[jn] = *(const bf16x8*)&Bs[r * 64 + slot * 8];
      }
#pragma unroll
      for (int im = 0; im < 4; ++im)
#pragma unroll
        for (int jn = 0; jn < 4; ++jn)
          acc[im][jn] = mfma16(af[im], bf[jn], acc[im][jn]);
    }
  }
  // epilogue: C/D layout col=lane&15, row=(lane>>4)*4+reg
  if (mode == 0) {
#pragma unroll
    for (int im = 0; im < 4; ++im)
#pragma unroll
      for (int jn = 0; jn < 4; ++jn) {
        const int n = n0 + wn * 64 + jn * 16 + l15;
        if (n < N) {
          const float badd = bias_n ? bias_n[n] : 0.f;
#pragma unroll
          for (int rg = 0; rg < 4; ++rg) {
            const int m = m0 + wm * 64 + im * 16 + q * 4 + rg;
            if (m < M) {
              float v = acc[im][jn][rg] + badd;
              if (auxBN) v += auxBN[(long)(m & 31) * auxld + n];
              C[(long)m * ldc + n] = v;
            }
          }
        }
      }
  } else {
    u64* G = (u64*)C;
#pragma unroll
    for (int im = 0; im < 4; ++im)
#pragma unroll
      for (int jn = 0; jn < 4; ++jn) {
        const int n = n0 + wn * 64 + jn * 16 + l15;
        const int dirsel = n >> 11, nn = n & 2047;
        const int gt = nn >> 9, u = nn & 511;
        const int ub = u >> 4, low = u & 15;
        const int wvl = low >> 2, jl = low & 3;
        const int l15l = gt * 4 + jl;
        const int m = m0 + wm * 64 + im * 16 + q * 4;   // rg=0 row
        const int s = m >> 5, b0 = m & 31;
        const int mh = b0 >> 4, qq = (b0 >> 2) & 3;
        const float badd = bias_n ? bias_n[n] : 0.f;
        u64 pk = 0;
#pragma unroll
        for (int rg = 0; rg < 4; ++rg) {
          float v = acc[im][jn][rg] + badd;
          if (auxBN) v += auxBN[(long)(b0 + rg) * auxld + n];
          pk |= (u64)f2bf(v) << (16 * rg);
        }
        G[(((((long)dirsel * 128 + s) * 2 + mh) * 32 + ub) * 4 + wvl) * 64
          + l15l * 4 + qq] = pk;
      }
  }
}

// ---------------------------------------------------------------------------
// persistent cooperative LSTM recurrence, one layer, both directions.
// 128 blocks x 256 thr: block = (dir, batch-half of 16, 16 hidden units).
// Dataflow sync: out pre-filled with bf16 NaN 0xFFFF; producers store h as
// atomic u64; consumers retry coalesced atomic u64 loads until non-sentinel.
// 4 independent MFMA accumulation chains.
// ---------------------------------------------------------------------------
__global__ __launch_bounds__(256, 1) void lstm_rec(
    const u16* __restrict__ gates,  // wave-ordered, see gemm_nt mode 1
    u16* __restrict__ out,          // [128][32][1024] bf16 (fwd | bwd)
    const u16* __restrict__ whh)    // [2][2048][512] bf16 (this layer)
{
  __shared__ __align__(16) u16 h_lds[16 * 512];
  __shared__ float gsc[4][16][17];
  const int bid = blockIdx.x;
  const int dir = bid >> 6;
  const int mh = (bid >> 5) & 1;
  const int ub = bid & 31;
  const int u0 = ub * 16;
  const int tid = threadIdx.x;
  const int wv = tid >> 6;
  const int ln = tid & 63;
  const int q = ln >> 4, l15 = ln & 15;

  // gate row for this lane's B-frag column n=l15: (n>>2)=gate type, (n&3)=unit
  const int gate_r = (l15 >> 2) * 512 + u0 + wv * 4 + (l15 & 3);

  bf16x8 bfrag[16];
  {
    const u16* wp = whh + ((long)dir * 2048 + gate_r) * 512 + q * 8;
#pragma unroll
    for (int ks = 0; ks < 16; ++ks)
      bfrag[ks] = *(const bf16x8*)(wp + ks * 32);
  }

  float c = 0.f;                       // cell state for (b_glob, j_lane)
  const int b_glob = mh * 16 + l15;    // batch (update phase)

  // wave-ordered gate pointer: stride per s = 2*32*4*64 = 16384 u64
  const u64* gbase = (const u64*)gates
      + ((((long)dir * 128 * 2 + mh) * 32 + ub) * 4 + wv) * 64 + l15 * 4 + q;

  u64 gcur = gbase[(long)(dir ? 127 : 0) * 16384];
  u64 gnext = 0;

  for (int t = 0; t < 128; ++t) {
    const int s = dir ? (127 - t) : t;
    // gate prefetch for t+1: coalesced 512 B per wave, issued before staging
    // so it completes alongside the staging loads; consumed next step.
    if (t < 127) {
      const int sn = dir ? (126 - t) : (t + 1);
      gnext = gbase[(long)sn * 16384];
    }
    floatx4 acc = (floatx4){0.f, 0.f, 0.f, 0.f};
    if (t > 0) {
      // stage h(t-1): 16 rows x 512 cols bf16. Coalesced device-scope u64
      // loads; each u64 = one producer wave's atomic store -> check low u16.
      const int sp = dir ? (s + 1) : (s - 1);
      const u64* ubp = (const u64*)(out + (((long)sp * 32 + mh * 16) * 1024 + (long)dir * 512));
      u64 v8[8];
#pragma unroll
      for (int j = 0; j < 8; ++j) {
        const int idx = j * 256 + tid;           // 2048 u64 chunks
        const int r = idx >> 7, c4 = idx & 127;  // row, u64-within-row
        v8[j] = aload64(ubp + (long)r * 256 + c4);
      }
      while (true) {
        bool bad = false;
#pragma unroll
        for (int j = 0; j < 8; ++j) bad |= ((v8[j] & 0xffffULL) == 0xffffULL);
        if (!bad) break;
#pragma unroll
        for (int j = 0; j < 8; ++j) {
          if ((v8[j] & 0xffffULL) == 0xffffULL) {
            const int idx = j * 256 + tid;
            const int r = idx >> 7, c4 = idx & 127;
            v8[j] = aload64(ubp + (long)r * 256 + c4);
          }
        }
      }
#pragma unroll
      for (int j = 0; j < 8; ++j) {
        const int idx = j * 256 + tid;
        const int r = idx >> 7, c4 = idx & 127;
        const int cc8 = c4 >> 1, hf = c4 & 1;
        *(u64*)&h_lds[r * 512 + ((cc8 ^ (r & 7)) << 3) + (hf << 2)] = v8[j];
      }
      __syncthreads();   // the ONLY barrier per step
      floatx4 acc1 = (floatx4){0.f, 0.f, 0.f, 0.f};
      floatx4 acc2 = (floatx4){0.f, 0.f, 0.f, 0.f};
      floatx4 acc3 = (floatx4){0.f, 0.f, 0.f, 0.f};
#pragma unroll
      for (int ks = 0; ks < 16; ks += 4) {   // 4 chains: 4-deep dep latency
        const int slot0 = (ks * 4 + q) ^ (l15 & 7);
        bf16x8 a0 = *(const bf16x8*)&h_lds[l15 * 512 + slot0 * 8];
        acc = mfma16(a0, bfrag[ks], acc);
        const int slot1 = ((ks + 1) * 4 + q) ^ (l15 & 7);
        bf16x8 a1 = *(const bf16x8*)&h_lds[l15 * 512 + slot1 * 8];
        acc1 = mfma16(a1, bfrag[ks + 1], acc1);
        const int slot2 = ((ks + 2) * 4 + q) ^ (l15 & 7);
        bf16x8 a2 = *(const bf16x8*)&h_lds[l15 * 512 + slot2 * 8];
        acc2 = mfma16(a2, bfrag[ks + 2], acc2);
        const int slot3 = ((ks + 3) * 4 + q) ^ (l15 & 7);
        bf16x8 a3 = *(const bf16x8*)&h_lds[l15 * 512 + slot3 * 8];
        acc3 = mfma16(a3, bfrag[ks + 3], acc3);
      }
      acc += acc1;
      acc2 += acc3;
      acc += acc2;
    }
    // C-frag (row=batch=q*4+rg, col=n=l15) -> wave-local LDS transpose
#pragma unroll
    for (int rg = 0; rg < 4; ++rg)
      gsc[wv][q * 4 + rg][l15] = acc[rg] + bf2f((u32)((gcur >> (16 * rg)) & 0xffffu));
    // gsc[wv] is touched only by wave wv: wave-synchronous, no barrier
    const float gi = gsc[wv][l15][q];
    const float gf = gsc[wv][l15][4 + q];
    const float gg = gsc[wv][l15][8 + q];
    const float go = gsc[wv][l15][12 + q];
    const float iv = sigf(gi), fv = sigf(gf), gv = tanh_(gg), ov = sigf(go);
    c = fv * c + iv * gv;
    const float h = ov * tanh_(c);
    // pack 4 units (quads q=0..3, lanes 16 apart) -> one u64 store by q==0
    const u32 hv = (u32)f2bf(h);
    const u32 p1 = (u32)__shfl_xor((int)hv, 16);
    const u32 lo32 = hv | (p1 << 16);
    const u64 w64 = (u64)lo32 |
                    ((u64)(u32)__shfl_xor((int)lo32, 32) << 32);
    if (q == 0)
      astore64(
          (u64*)&out[((long)s * 32 + b_glob) * 1024 + dir * 512 + u0 + wv * 4],
          w64);
    gcur = gnext;
  }
}

// ---------------------------------------------------------------------------
// CRF: one block per (task, batch). Double-buffered alpha: 1 barrier/step.
// ---------------------------------------------------------------------------
template <int K>
static __device__ void crf_body(const float* __restrict__ feat, int off,
                                const int* __restrict__ labels, int b,
                                const float* __restrict__ start,
                                const float* __restrict__ end_,
                                const float* __restrict__ trans,
                                float* __restrict__ outp,
                                float* transT, float (*alpha)[64],
                                float* red)
{
  const int tid = threadIdx.x;
  for (int i = tid; i < K * K; i += 256) {
    int kk = i / K, kp2 = i % K;
    transT[kp2 * 65 + kk] = trans[i];
  }
  if (tid < K) alpha[0][tid] = start[tid] + feat[b * 96 + off + tid];
  __syncthreads();
  constexpr int Kq = K / 4;
  const int kp = tid >> 2, k4 = tid & 3;
  const bool act = kp < K;
  int p = 0;
  for (int s = 1; s < 128; ++s) {
    float x[Kq];
    float mx = -3e38f;
    if (act) {
      const float* tr = &transT[kp * 65 + k4 * Kq];
      const float* al = &alpha[p][k4 * Kq];
#pragma unroll
      for (int i2 = 0; i2 < Kq; ++i2) { x[i2] = al[i2] + tr[i2]; mx = fmaxf(mx, x[i2]); }
    }
    mx = fmaxf(mx, __shfl_xor(mx, 1));
    mx = fmaxf(mx, __shfl_xor(mx, 2));
    float ss = 0.f;
    if (act) {
#pragma unroll
      for (int i2 = 0; i2 < Kq; ++i2) ss += __expf(x[i2] - mx);
    }
    ss += __shfl_xor(ss, 1);
    ss += __shfl_xor(ss, 2);
    if (act && k4 == 0)
      alpha[p ^ 1][kp] = mx + __logf(ss) + feat[(s * 32 + b) * 96 + off + kp];
    __syncthreads();
    p ^= 1;
  }
  // numerator terms (one per time step)
  if (tid < 128) {
    const int tg = labels[tid * 32 + b];
    float term = feat[(tid * 32 + b) * 96 + off + tg];
    if (tid == 0) term += start[tg];
    else          term += trans[labels[(tid - 1) * 32 + b] * K + tg];
    if (tid == 127) term += end_[tg];
    red[tid] = term;
  }
  __syncthreads();
  if (tid == 0) {
    float num = 0.f;
    for (int i = 0; i < 128; ++i) num += red[i];
    float mx = -3e38f;
    for (int k = 0; k < K; ++k) mx = fmaxf(mx, alpha[p][k] + end_[k]);
    float ss = 0.f;
    for (int k = 0; k < K; ++k) ss += __expf(alpha[p][k] + end_[k] - mx);
    const float den = mx + __logf(ss);
    atomicAdd(outp, den - num);   // loss contribution = -(num - den)
  }
}

__global__ __launch_bounds__(256) void crf_kernel(
    const float* __restrict__ feat,
    const int* __restrict__ labp, const int* __restrict__ labm,
    const float* __restrict__ stp, const float* __restrict__ enp, const float* __restrict__ trp,
    const float* __restrict__ stm, const float* __restrict__ enm, const float* __restrict__ trm,
    float* __restrict__ outp)
{
  __shared__ float transT[64 * 65];
  __shared__ float alpha[2][64];
  __shared__ float red[128];
  const int task = blockIdx.x >> 5, b = blockIdx.x & 31;
  if (task == 0) crf_body<32>(feat, 0,  labp, b, stp, enp, trp, outp, transT, alpha, red);
  else           crf_body<64>(feat, 32, labm, b, stm, enm, trm, outp, transT, alpha, red);
}

// ---------------------------------------------------------------------------
// launch
// ---------------------------------------------------------------------------
extern "C" void kernel_launch(void* const* d_in, const int* in_sizes, int n_in,
                              void* d_out, int out_size, void* d_ws, size_t ws_size,
                              hipStream_t stream) {
  const float* src  = (const float*)d_in[0];
  const float* bert = (const float*)d_in[1];
  const int*   labp = (const int*)d_in[2];
  const int*   labm = (const int*)d_in[3];
  const float* w_ih = (const float*)d_in[4];
  const float* w_hh = (const float*)d_in[5];
  const float* b_ih = (const float*)d_in[6];
  const float* b_hh = (const float*)d_in[7];
  const float* hwp  = (const float*)d_in[8];
  const float* hbp  = (const float*)d_in[9];
  const float* hwm  = (const float*)d_in[10];
  const float* hbm  = (const float*)d_in[11];
  const float* stp  = (const float*)d_in[12];
  const float* enp  = (const float*)d_in[13];
  const float* trp  = (const float*)d_in[14];
  const float* stm  = (const float*)d_in[15];
  const float* enm  = (const float*)d_in[16];
  const float* trm  = (const float*)d_in[17];

  char* ws = (char*)d_ws;
  u16*   Wsrc     = (u16*)(ws + 0);          // 4096x256 bf16
  u16*   Wbert    = (u16*)(ws + 2097152);    // 4096x768 bf16
  u16*   Wih1     = (u16*)(ws + 8388608);    // 4096x1024 bf16
  u16*   Whh      = (u16*)(ws + 16777216);   // [2][2][2048][512] bf16
  u16*   SrcBf    = (u16*)(ws + 25165824);   // 4096x256 bf16
  u16*   BertBf   = (u16*)(ws + 27262976);   // 32x768 bf16
  u16*   Wheads   = (u16*)(ws + 27312128);   // 96x1024 bf16
  float* b0sum    = (float*)(ws + 27508736); // [4096]
  float* b1sum    = (float*)(ws + 27525120); // [4096]
  float* hb       = (float*)(ws + 27541504); // [96]
  float* bertpart = (float*)(ws + 27542272); // [32][4096]
  float* feat     = (float*)(ws + 28066560); // [4096][96]
  u16*   out0     = (u16*)(ws + 29639424);   // [128][32][1024] bf16
  u16*   out1     = (u16*)(ws + 38028032);   // [128][32][1024] bf16
  u16*   gates    = (u16*)(ws + 46416640);   // wave-ordered bf16 (32 MiB)
  float* dout     = (float*)d_out;

  // prep: conversions + bias sums + dout=0 + sentinel fill of out0/out1
  hipLaunchKernelGGL(prep_kernel, dim3(2048), dim3(256), 0, stream,
      w_ih, w_hh, b_ih, b_hh, src, bert, hwp, hbp, hwm, hbm,
      Wsrc, Wbert, Wih1, Whh, SrcBf, BertBf, Wheads, b0sum, b1sum, hb, dout,
      (u64*)out0, (u64*)out1);

  // bert part: [32,768]@[4096,768]^T + (b_ih0+b_hh0) -> bertpart[32][4096]
  hipLaunchKernelGGL(gemm_nt, dim3(32, 1), dim3(256), 0, stream,
      BertBf, 768, Wbert, 768, bertpart, 4096, 32, 4096, 768,
      b0sum, (const float*)nullptr, 0, 0);

  // layer0 input proj: src@Wsrc^T + bertpart -> bf16 gates (wave-ordered)
  hipLaunchKernelGGL(gemm_nt, dim3(32, 32), dim3(256), 0, stream,
      SrcBf, 256, Wsrc, 256, (float*)gates, 0, 4096, 4096, 256,
      (const float*)nullptr, bertpart, 4096, 1);

  {
    const u16* g = gates; u16* o = out0; const u16* wh = Whh;
    void* args[] = {&g, &o, &wh};
    if (hipLaunchCooperativeKernel(reinterpret_cast<void*>(&lstm_rec),
                                   dim3(128), dim3(256), args, 0, stream)
        != hipSuccess) {
      hipLaunchKernelGGL(lstm_rec, dim3(128), dim3(256), 0, stream, g, o, wh);
    }
  }

  // layer1 input proj: out0@Wih1^T + b1sum -> bf16 gates (wave-ordered)
  hipLaunchKernelGGL(gemm_nt, dim3(32, 32), dim3(256), 0, stream,
      out0, 1024, Wih1, 1024, (float*)gates, 0, 4096, 4096, 1024,
      b1sum, (const float*)nullptr, 0, 1);

  {
    const u16* g = gates; u16* o = out1; const u16* wh = Whh + 2L * 2048 * 512;
    void* args[] = {&g, &o, &wh};
    if (hipLaunchCooperativeKernel(reinterpret_cast<void*>(&lstm_rec),
                                   dim3(128), dim3(256), args, 0, stream)
        != hipSuccess) {
      hipLaunchKernelGGL(lstm_rec, dim3(128), dim3(256), 0, stream, g, o, wh);
    }
  }

  // heads: out1@[96,1024]^T + hb -> feat[4096][96]
  hipLaunchKernelGGL(gemm_nt, dim3(1, 32), dim3(256), 0, stream,
      out1, 1024, Wheads, 1024, feat, 96, 4096, 96, 1024,
      hb, (const float*)nullptr, 0, 0);

  hipLaunchKernelGGL(crf_kernel, dim3(64), dim3(256), 0, stream,
      feat, labp, labm, stp, enp, trp, stm, enm, trm, dout);
}